// Round 8
// baseline (197.412 us; speedup 1.0000x reference)
//
#include <hip/hip_runtime.h>

// GConvGRU with H=0: only two ChebConvs on X survive.
//   Z  = sigmoid(X@Wz0 + Tx1@Wz1 + Tx2@Wz2 + b_xz + b_hz)
//   Ht = tanh   (X@Wh0 + Tx1@Wh1 + Tx2@Wh2 + b_xh + b_hh)
//   H_new = (1-Z)*Ht
// Build: LDS bucket binning (no global atomics) -> per-bucket ELL(W=48)
// + CSR overflow, val = -w*dinv[s]*dinv[d] folded. Fixed-width ELL loop
// gives ~8+ outstanding gathers/lane (vs ~4 on dynamic CSR loop).
// GRU GEMM: bf16x3 split-precision MFMA (fp32 accum), err ~2e-5.
// ws_size proven = 256 MiB (harness poison fill), usage here ~51.6 MB.

#define N_NODES 50000
#define E_EDGES 800000
#define NC 64
#define BSH 6                 // 64 nodes per bucket
#define BUKN 64
#define NBUK 782              // ceil(50000/64)
#define EPB 2048              // edges per hist/scatter block
#define NBLK 391              // ceil(800000/2048)
#define ELLW 48               // ELL width (avg deg 16; overflow -> CSR)

// ws element offsets (4B units); aliases are dead before their host buffer is written
#define OFF_CV       0          // long long[800000] (CSR overflow slots only)
#define OFF_ROWSTART 1600000    // int[50001] (pad 50016)
#define OFF_TOTD     1650016    // int[784]
#define OFF_BASED    1650800    // int[784]
#define OFF_TOTS     1651584    // int[784]
#define OFF_BASES    1652368    // int[784]
#define OFF_TX1      1653152    // float[3200000]
#define OFF_RECD     1653152    //   alias: long long[800000], dead after k_csr
#define OFF_DINV     3253152    //   alias: float[50016], dead after k_csr
#define OFF_CNTD     3303168    //   alias: int[782*391], dead after k_scatter
#define OFF_TX2      4853152    // float[3200000] (ends 8053152)
#define OFF_RECS     4853152    //   alias: long long[800000], dead after k_deg
#define OFF_CNTS     6453152    //   alias: int[782*391], dead after k_scatter
#define OFF_WB       8053152    // short[49152] bf16 weight planes (ends 8077728)
#define OFF_ELL      8077824    // long long[50176*48] (ends 12894720 = 51.6MB)

typedef __attribute__((ext_vector_type(8))) short bf16x8;
typedef __attribute__((ext_vector_type(4))) float f32x4;

__device__ __forceinline__ unsigned bf16rne(float x) {
    unsigned u = __float_as_uint(x);
    return (u + 0x7fffu + ((u >> 16) & 1u)) >> 16;
}

// hist blocks bin edges; extra 6 blocks build bf16 weight planes (prepw).
__global__ __launch_bounds__(256) void k_hist(const int* __restrict__ ei,
        int* __restrict__ cntD, int* __restrict__ cntS,
        const float* __restrict__ Wz, const float* __restrict__ Wh,
        short* __restrict__ WB) {
    int t = threadIdx.x, blk = blockIdx.x;
    if (blk >= NBLK) {                  // prepw part
        int mg = blk - NBLK;            // 0..5 = (m,g)
        int m = mg >> 1, g = mg & 1;
        const float* W = (g ? Wh : Wz) + m * 4096;
        #pragma unroll
        for (int r = 0; r < 16; ++r) {
            int idx = r * 256 + t;      // c*64 + o
            int c = idx >> 6, o = idx & 63;
            float x = W[idx];
            unsigned hi = bf16rne(x);
            float fhi = __uint_as_float(hi << 16);
            unsigned lo = bf16rne(x - fhi);
            WB[(mg * 2 + 0) * 4096 + o * 64 + c] = (short)hi;
            WB[(mg * 2 + 1) * 4096 + o * 64 + c] = (short)lo;
        }
        return;
    }
    __shared__ int hD[NBUK], hS[NBUK];
    for (int b = t; b < NBUK; b += 256) { hD[b] = 0; hS[b] = 0; }
    __syncthreads();
    int e0 = blk * EPB;
    #pragma unroll
    for (int i = 0; i < 8; ++i) {
        int e = e0 + i * 256 + t;
        if (e < E_EDGES) {
            atomicAdd(&hS[ei[e] >> BSH], 1);
            atomicAdd(&hD[ei[E_EDGES + e] >> BSH], 1);
        }
    }
    __syncthreads();
    for (int b = t; b < NBUK; b += 256) {
        cntD[b * NBLK + blk] = hD[b];
        cntS[b * NBLK + blk] = hS[b];
    }
}

__global__ __launch_bounds__(256) void k_scanPB(int* __restrict__ cntD,
        int* __restrict__ cntS, int* __restrict__ totD, int* __restrict__ totS) {
    __shared__ int s[512];
    int t = threadIdx.x;
    int row = blockIdx.x; int* cnt; int* tot;
    if (row < NBUK) { cnt = cntD; tot = totD; }
    else            { row -= NBUK; cnt = cntS; tot = totS; }
    int v0 = (t < NBLK) ? cnt[row * NBLK + t] : 0;
    int v1 = (256 + t < NBLK) ? cnt[row * NBLK + 256 + t] : 0;
    s[t] = v0; s[256 + t] = v1;
    __syncthreads();
    for (int off = 1; off < 512; off <<= 1) {
        int a = (t >= off) ? s[t - off] : 0;
        int b = (256 + t >= off) ? s[256 + t - off] : 0;
        __syncthreads();
        s[t] += a; s[256 + t] += b;
        __syncthreads();
    }
    if (t < NBLK) cnt[row * NBLK + t] = s[t] - v0;
    if (256 + t < NBLK) cnt[row * NBLK + 256 + t] = s[256 + t] - v1;
    if (t == 0) tot[row] = s[511];
}

__global__ __launch_bounds__(256) void k_scanTot(int* __restrict__ totD,
        int* __restrict__ baseD, int* __restrict__ totS, int* __restrict__ baseS) {
    __shared__ int s[1024];
    int t = threadIdx.x;
    int* tot  = blockIdx.x ? totS  : totD;
    int* base = blockIdx.x ? baseS : baseD;
    int v[4];
    #pragma unroll
    for (int q = 0; q < 4; ++q) {
        int i = q * 256 + t;
        v[q] = (i < NBUK) ? tot[i] : 0;
        s[i] = v[q];
    }
    __syncthreads();
    for (int off = 1; off < 1024; off <<= 1) {
        int a[4];
        #pragma unroll
        for (int q = 0; q < 4; ++q) {
            int i = q * 256 + t;
            a[q] = (i >= off) ? s[i - off] : 0;
        }
        __syncthreads();
        #pragma unroll
        for (int q = 0; q < 4; ++q) s[q * 256 + t] += a[q];
        __syncthreads();
    }
    #pragma unroll
    for (int q = 0; q < 4; ++q) {
        int i = q * 256 + t;
        if (i < NBUK) base[i] = s[i] - v[q];
    }
}

__global__ __launch_bounds__(256) void k_scatter(const int* __restrict__ ei,
        const float* __restrict__ ew, const int* __restrict__ offD,
        const int* __restrict__ offS, const int* __restrict__ baseD,
        const int* __restrict__ baseS, long long* __restrict__ recD,
        long long* __restrict__ recS) {
    __shared__ int curD[NBUK], curS[NBUK];
    int t = threadIdx.x, blk = blockIdx.x;
    for (int b = t; b < NBUK; b += 256) {
        curD[b] = baseD[b] + offD[b * NBLK + blk];
        curS[b] = baseS[b] + offS[b * NBLK + blk];
    }
    __syncthreads();
    int e0 = blk * EPB;
    #pragma unroll
    for (int i = 0; i < 8; ++i) {
        int e = e0 + i * 256 + t;
        if (e < E_EDGES) {
            int sN = ei[e], dN = ei[E_EDGES + e];
            long long wb = (long long)(unsigned)__float_as_uint(ew[e]) << 32;
            int pD = atomicAdd(&curD[dN >> BSH], 1);
            recD[pD] = wb | (unsigned)((sN << BSH) | (dN & (BUKN - 1)));
            int pS = atomicAdd(&curS[sN >> BSH], 1);
            recS[pS] = wb | (unsigned)(sN & (BUKN - 1));
        }
    }
}

__global__ __launch_bounds__(256) void k_deg(const long long* __restrict__ recS,
        const int* __restrict__ totS, const int* __restrict__ baseS,
        float* __restrict__ dinv) {
    __shared__ float degL[BUKN];
    int t = threadIdx.x, b = blockIdx.x;
    if (t < BUKN) degL[t] = 0.f;
    __syncthreads();
    int st = baseS[b], n = totS[b];
    for (int i = t; i < n; i += 256) {
        long long r = recS[st + i];
        atomicAdd(&degL[(int)(r & (BUKN - 1))], __uint_as_float((unsigned)(r >> 32)));
    }
    __syncthreads();
    if (t < BUKN) {
        int node = b * BUKN + t;
        if (node < N_NODES) {
            float dg = degL[t];
            dinv[node] = dg > 0.f ? rsqrtf(dg) : 0.f;
        }
    }
}

// Bucket records -> ELL (k<ELLW) + CSR overflow (k>=ELLW), val folded.
// Pads zero-filled. Emits row_start (global CSR offsets, used for cnt+overflow).
__global__ __launch_bounds__(256) void k_csr(const long long* __restrict__ recD,
        const int* __restrict__ totD, const int* __restrict__ baseD,
        const float* __restrict__ dinv, long long* __restrict__ cv,
        long long* __restrict__ ell, int* __restrict__ row_start) {
    __shared__ int cnt[BUKN], rb[BUKN], cur[BUKN];
    __shared__ float dL[BUKN];
    int t = threadIdx.x, b = blockIdx.x;
    if (t < BUKN) {
        cnt[t] = 0;
        cur[t] = 0;
        int node = b * BUKN + t;
        dL[t] = (node < N_NODES) ? dinv[node] : 0.f;
    }
    __syncthreads();
    int st = baseD[b], n = totD[b];
    for (int i = t; i < n; i += 256)
        atomicAdd(&cnt[(int)(recD[st + i] & (BUKN - 1))], 1);
    __syncthreads();
    if (t < BUKN) {
        int x = cnt[t];
        int orig = x;
        #pragma unroll
        for (int off = 1; off < BUKN; off <<= 1) {
            int v = __shfl_up(x, off, 64);
            if ((t & 63) >= off) x += v;
        }
        rb[t] = x - orig;
        int node = b * BUKN + t;
        if (node < N_NODES) row_start[node] = st + (x - orig);
    }
    if (b == 0 && t == 0) row_start[N_NODES] = E_EDGES;
    __syncthreads();
    for (int i = t; i < n; i += 256) {
        long long r = recD[st + i];
        int m = (int)(r & 0xffffffffLL);
        float w = __uint_as_float((unsigned)(r >> 32));
        int rr = m & (BUKN - 1);
        int sN = m >> BSH;
        float val = -w * dinv[sN] * dL[rr];
        long long rec = ((long long)__float_as_int(val) << 32) | (unsigned)sN;
        int k = atomicAdd(&cur[rr], 1);
        if (k < ELLW) ell[(size_t)(b * BUKN + rr) * ELLW + k] = rec;
        else          cv[st + rb[rr] + k] = rec;
    }
    __syncthreads();
    // zero-fill ELL pads (val=0, src=0 -> gather hits hot line, fma adds 0)
    for (int idx = t; idx < BUKN * ELLW; idx += 256) {
        int rr = idx / ELLW, k = idx - rr * ELLW;
        if (k >= cnt[rr]) ell[(size_t)(b * BUKN + rr) * ELLW + k] = 0LL;
    }
}

// Pull-mode SpMM over ELL: one wave per row, lane = channel.
// Fixed trip count -> 8-deep independent gather chains.
template<int SCALE, int SUB>
__global__ __launch_bounds__(256) void k_spmm(
        const int* __restrict__ row_start, const long long* __restrict__ ell,
        const long long* __restrict__ cv, const float* __restrict__ xin,
        const float* __restrict__ xprev, float* __restrict__ out) {
    int wid = (blockIdx.x << 2) + (threadIdx.x >> 6);
    int lane = threadIdx.x & 63;
    if (wid >= N_NODES) return;
    const long long* er = ell + (size_t)wid * ELLW;
    float acc = 0.f;
    #pragma unroll
    for (int c = 0; c < ELLW; c += 8) {
        long long p[8];
        #pragma unroll
        for (int k = 0; k < 8; ++k) p[k] = er[c + k];
        float xv[8];
        #pragma unroll
        for (int k = 0; k < 8; ++k)
            xv[k] = xin[(size_t)(unsigned)(p[k] & 0xffffffffLL) * NC + lane];
        #pragma unroll
        for (int k = 0; k < 8; ++k)
            acc = fmaf(__int_as_float((int)(p[k] >> 32)), xv[k], acc);
    }
    int start = row_start[wid];
    int end   = row_start[wid + 1];
    if (end - start > ELLW) {       // overflow (approx never, but correct)
        for (int j = start + ELLW; j < end; ++j) {
            long long p = cv[j];
            int s = (int)(p & 0xffffffffLL);
            acc = fmaf(__int_as_float((int)(p >> 32)), xin[(size_t)s * NC + lane], acc);
        }
    }
    float r = (float)SCALE * acc;
    if (SUB) r -= xprev[(size_t)wid * NC + lane];
    out[(size_t)wid * NC + lane] = r;
}

// bf16x3 MFMA GRU: 64-node tile, 4 waves = 4 o-tiles of 16 channels.
__global__ __launch_bounds__(256) void k_gru(
        const float* __restrict__ X, const float* __restrict__ Tx1,
        const float* __restrict__ Tx2, const short* __restrict__ WB,
        const float* __restrict__ bxz, const float* __restrict__ bhz,
        const float* __restrict__ bxh, const float* __restrict__ bhh,
        float* __restrict__ out) {
    __shared__ short Ahi[64 * 64];
    __shared__ short Alo[64 * 64];
    int tid = threadIdx.x;
    int l = tid & 63;
    int w = tid >> 6;
    int node0 = blockIdx.x * 64;

    f32x4 accz[4], acch[4];
    #pragma unroll
    for (int mt = 0; mt < 4; ++mt) {
        accz[mt] = (f32x4){0.f, 0.f, 0.f, 0.f};
        acch[mt] = (f32x4){0.f, 0.f, 0.f, 0.f};
    }

    const float* ins[3] = {X, Tx1, Tx2};
    #pragma unroll 1
    for (int m = 0; m < 3; ++m) {
        __syncthreads();
        const float* ip = ins[m];
        #pragma unroll
        for (int r = 0; r < 4; ++r) {
            int fidx = r * 256 + tid;
            int n = fidx >> 4, c4 = fidx & 15;
            int gn = node0 + n;
            float4 v = make_float4(0.f, 0.f, 0.f, 0.f);
            if (gn < N_NODES) v = *(const float4*)&ip[(size_t)gn * 64 + c4 * 4];
            unsigned h0 = bf16rne(v.x), h1 = bf16rne(v.y),
                     h2 = bf16rne(v.z), h3 = bf16rne(v.w);
            unsigned q0 = bf16rne(v.x - __uint_as_float(h0 << 16));
            unsigned q1 = bf16rne(v.y - __uint_as_float(h1 << 16));
            unsigned q2 = bf16rne(v.z - __uint_as_float(h2 << 16));
            unsigned q3 = bf16rne(v.w - __uint_as_float(h3 << 16));
            int kk = (c4 * 4) ^ ((n & 7) << 3);
            *(uint2*)&Ahi[n * 64 + kk] = make_uint2(h0 | (h1 << 16), h2 | (h3 << 16));
            *(uint2*)&Alo[n * 64 + kk] = make_uint2(q0 | (q1 << 16), q2 | (q3 << 16));
        }
        __syncthreads();
        const short* wbm = WB + m * 4 * 4096;
        #pragma unroll
        for (int kt = 0; kt < 2; ++kt) {
            int k0 = kt * 32 + (l >> 4) * 8;
            bf16x8 ah[4], al[4];
            #pragma unroll
            for (int mt = 0; mt < 4; ++mt) {
                int row = mt * 16 + (l & 15);
                int kk = k0 ^ ((row & 7) << 3);
                ah[mt] = *(const bf16x8*)&Ahi[row * 64 + kk];
                al[mt] = *(const bf16x8*)&Alo[row * 64 + kk];
            }
            int o = w * 16 + (l & 15);
            {
                bf16x8 bh_ = *(const bf16x8*)&wbm[0 * 4096 + o * 64 + k0];
                bf16x8 bl_ = *(const bf16x8*)&wbm[1 * 4096 + o * 64 + k0];
                #pragma unroll
                for (int mt = 0; mt < 4; ++mt) {
                    accz[mt] = __builtin_amdgcn_mfma_f32_16x16x32_bf16(ah[mt], bh_, accz[mt], 0, 0, 0);
                    accz[mt] = __builtin_amdgcn_mfma_f32_16x16x32_bf16(ah[mt], bl_, accz[mt], 0, 0, 0);
                    accz[mt] = __builtin_amdgcn_mfma_f32_16x16x32_bf16(al[mt], bh_, accz[mt], 0, 0, 0);
                }
            }
            {
                bf16x8 bh_ = *(const bf16x8*)&wbm[2 * 4096 + o * 64 + k0];
                bf16x8 bl_ = *(const bf16x8*)&wbm[3 * 4096 + o * 64 + k0];
                #pragma unroll
                for (int mt = 0; mt < 4; ++mt) {
                    acch[mt] = __builtin_amdgcn_mfma_f32_16x16x32_bf16(ah[mt], bh_, acch[mt], 0, 0, 0);
                    acch[mt] = __builtin_amdgcn_mfma_f32_16x16x32_bf16(ah[mt], bl_, acch[mt], 0, 0, 0);
                    acch[mt] = __builtin_amdgcn_mfma_f32_16x16x32_bf16(al[mt], bh_, acch[mt], 0, 0, 0);
                }
            }
        }
    }

    int o = w * 16 + (l & 15);
    float bz = bxz[o] + bhz[o];
    float bh = bxh[o] + bhh[o];
    #pragma unroll
    for (int mt = 0; mt < 4; ++mt) {
        #pragma unroll
        for (int r = 0; r < 4; ++r) {
            int node = node0 + mt * 16 + (l >> 4) * 4 + r;
            if (node < N_NODES) {
                float z = accz[mt][r] + bz;
                float h = acch[mt][r] + bh;
                float sig = 1.f / (1.f + __expf(-z));
                float e2 = __expf(-2.f * h);
                float th = (1.f - e2) / (1.f + e2);
                out[(size_t)node * 64 + o] = (1.f - sig) * th;
            }
        }
    }
}

extern "C" void kernel_launch(void* const* d_in, const int* in_sizes, int n_in,
                              void* d_out, int out_size, void* d_ws, size_t ws_size,
                              hipStream_t stream) {
    const float* X   = (const float*)d_in[0];
    const int*   ei  = (const int*)d_in[1];
    const float* ew  = (const float*)d_in[2];
    const float* Wxz = (const float*)d_in[3];
    const float* Wxh = (const float*)d_in[7];
    const float* bxz = (const float*)d_in[9];
    const float* bhz = (const float*)d_in[10];
    const float* bxh = (const float*)d_in[13];
    const float* bhh = (const float*)d_in[14];
    float* out = (float*)d_out;

    float* ws_f = (float*)d_ws;
    int*   ws_i = (int*)d_ws;

    long long* cv       = (long long*)(ws_i + OFF_CV);
    int*       rowstart = ws_i + OFF_ROWSTART;
    int*       totD     = ws_i + OFF_TOTD;
    int*       baseD    = ws_i + OFF_BASED;
    int*       totS     = ws_i + OFF_TOTS;
    int*       baseS    = ws_i + OFF_BASES;
    float*     tx1      = ws_f + OFF_TX1;
    long long* recD     = (long long*)(ws_i + OFF_RECD);
    float*     dinv     = ws_f + OFF_DINV;
    int*       cntD     = ws_i + OFF_CNTD;
    float*     tx2      = ws_f + OFF_TX2;
    long long* recS     = (long long*)(ws_i + OFF_RECS);
    int*       cntS     = ws_i + OFF_CNTS;
    short*     WB       = (short*)(ws_i + OFF_WB);
    long long* ell      = (long long*)(ws_i + OFF_ELL);

    const int TB = 256;
    k_hist<<<NBLK + 6, TB, 0, stream>>>(ei, cntD, cntS, Wxz, Wxh, WB);
    k_scanPB<<<2 * NBUK, TB, 0, stream>>>(cntD, cntS, totD, totS);
    k_scanTot<<<2, TB, 0, stream>>>(totD, baseD, totS, baseS);
    k_scatter<<<NBLK, TB, 0, stream>>>(ei, ew, cntD, cntS, baseD, baseS, recD, recS);
    k_deg<<<NBUK, TB, 0, stream>>>(recS, totS, baseS, dinv);
    k_csr<<<NBUK, TB, 0, stream>>>(recD, totD, baseD, dinv, cv, ell, rowstart);

    // Tx1 = L_hat @ X
    k_spmm<1, 0><<<(N_NODES + 3) / 4, TB, 0, stream>>>(rowstart, ell, cv, X, X, tx1);
    // Tx2 = 2 * L_hat @ Tx1 - X
    k_spmm<2, 1><<<(N_NODES + 3) / 4, TB, 0, stream>>>(rowstart, ell, cv, tx1, X, tx2);

    k_gru<<<NBUK, TB, 0, stream>>>(X, tx1, tx2, WB, bxz, bhz, bxh, bhh, out);
}

// Round 9
// 147.006 us; speedup vs baseline: 1.3429x; 1.3429x over previous
//
#include <hip/hip_runtime.h>

// GConvGRU with H=0: only two ChebConvs on X survive.
//   Z  = sigmoid(X@Wz0 + Tx1@Wz1 + Tx2@Wz2 + b_xz + b_hz)
//   Ht = tanh   (X@Wh0 + Tx1@Wh1 + Tx2@Wh2 + b_xh + b_hh)
//   H_new = (1-Z)*Ht
// Build: LDS bucket binning (no global atomics) -> per-bucket exact CSR
// (val = -w*dinv[s]*dinv[d] folded). SpMM: 16 lanes/edge x 4 edges/instr
// float4 gathers (4x fewer VMEM instrs than row-wave scalar; R8 showed
// spmm time ~ gather instruction count). GRU: bf16x3 MFMA.

#define N_NODES 50000
#define E_EDGES 800000
#define NC 64
#define BSH 6                 // 64 nodes per bucket
#define BUKN 64
#define NBUK 782              // ceil(50000/64)
#define EPB 2048              // edges per hist/scatter block
#define NBLK 391              // ceil(800000/2048)

// ws element offsets (4B units); aliases are dead before their host buffer is written
#define OFF_CV       0          // long long[800000] (exact CSR: val|src)
#define OFF_ROWSTART 1600000    // int[50001] (pad 50016)
#define OFF_TOTD     1650016    // int[784]
#define OFF_BASED    1650800    // int[784]
#define OFF_TOTS     1651584    // int[784]
#define OFF_BASES    1652368    // int[784]
#define OFF_TX1      1653152    // float[3200000]
#define OFF_RECD     1653152    //   alias: long long[800000], dead after k_csr
#define OFF_DINV     3253152    //   alias: float[50016], dead after k_csr
#define OFF_CNTD     3303168    //   alias: int[782*391], dead after k_scatter
#define OFF_TX2      4853152    // float[3200000] (ends 8053152)
#define OFF_RECS     4853152    //   alias: long long[800000], dead after k_deg
#define OFF_CNTS     6453152    //   alias: int[782*391], dead after k_scatter
#define OFF_WB       8053152    // short[49152] bf16 weight planes (past TX2)

typedef __attribute__((ext_vector_type(8))) short bf16x8;
typedef __attribute__((ext_vector_type(4))) float f32x4;

__device__ __forceinline__ unsigned bf16rne(float x) {
    unsigned u = __float_as_uint(x);
    return (u + 0x7fffu + ((u >> 16) & 1u)) >> 16;
}

// hist blocks bin edges; extra 6 blocks build bf16 weight planes (prepw).
__global__ __launch_bounds__(256) void k_hist(const int* __restrict__ ei,
        int* __restrict__ cntD, int* __restrict__ cntS,
        const float* __restrict__ Wz, const float* __restrict__ Wh,
        short* __restrict__ WB) {
    int t = threadIdx.x, blk = blockIdx.x;
    if (blk >= NBLK) {                  // prepw part
        int mg = blk - NBLK;            // 0..5 = (m,g)
        int m = mg >> 1, g = mg & 1;
        const float* W = (g ? Wh : Wz) + m * 4096;
        #pragma unroll
        for (int r = 0; r < 16; ++r) {
            int idx = r * 256 + t;      // c*64 + o
            int c = idx >> 6, o = idx & 63;
            float x = W[idx];
            unsigned hi = bf16rne(x);
            float fhi = __uint_as_float(hi << 16);
            unsigned lo = bf16rne(x - fhi);
            WB[(mg * 2 + 0) * 4096 + o * 64 + c] = (short)hi;
            WB[(mg * 2 + 1) * 4096 + o * 64 + c] = (short)lo;
        }
        return;
    }
    __shared__ int hD[NBUK], hS[NBUK];
    for (int b = t; b < NBUK; b += 256) { hD[b] = 0; hS[b] = 0; }
    __syncthreads();
    int e0 = blk * EPB;
    #pragma unroll
    for (int i = 0; i < 8; ++i) {
        int e = e0 + i * 256 + t;
        if (e < E_EDGES) {
            atomicAdd(&hS[ei[e] >> BSH], 1);
            atomicAdd(&hD[ei[E_EDGES + e] >> BSH], 1);
        }
    }
    __syncthreads();
    for (int b = t; b < NBUK; b += 256) {
        cntD[b * NBLK + blk] = hD[b];
        cntS[b * NBLK + blk] = hS[b];
    }
}

__global__ __launch_bounds__(256) void k_scanPB(int* __restrict__ cntD,
        int* __restrict__ cntS, int* __restrict__ totD, int* __restrict__ totS) {
    __shared__ int s[512];
    int t = threadIdx.x;
    int row = blockIdx.x; int* cnt; int* tot;
    if (row < NBUK) { cnt = cntD; tot = totD; }
    else            { row -= NBUK; cnt = cntS; tot = totS; }
    int v0 = (t < NBLK) ? cnt[row * NBLK + t] : 0;
    int v1 = (256 + t < NBLK) ? cnt[row * NBLK + 256 + t] : 0;
    s[t] = v0; s[256 + t] = v1;
    __syncthreads();
    for (int off = 1; off < 512; off <<= 1) {
        int a = (t >= off) ? s[t - off] : 0;
        int b = (256 + t >= off) ? s[256 + t - off] : 0;
        __syncthreads();
        s[t] += a; s[256 + t] += b;
        __syncthreads();
    }
    if (t < NBLK) cnt[row * NBLK + t] = s[t] - v0;
    if (256 + t < NBLK) cnt[row * NBLK + 256 + t] = s[256 + t] - v1;
    if (t == 0) tot[row] = s[511];
}

__global__ __launch_bounds__(256) void k_scanTot(int* __restrict__ totD,
        int* __restrict__ baseD, int* __restrict__ totS, int* __restrict__ baseS) {
    __shared__ int s[1024];
    int t = threadIdx.x;
    int* tot  = blockIdx.x ? totS  : totD;
    int* base = blockIdx.x ? baseS : baseD;
    int v[4];
    #pragma unroll
    for (int q = 0; q < 4; ++q) {
        int i = q * 256 + t;
        v[q] = (i < NBUK) ? tot[i] : 0;
        s[i] = v[q];
    }
    __syncthreads();
    for (int off = 1; off < 1024; off <<= 1) {
        int a[4];
        #pragma unroll
        for (int q = 0; q < 4; ++q) {
            int i = q * 256 + t;
            a[q] = (i >= off) ? s[i - off] : 0;
        }
        __syncthreads();
        #pragma unroll
        for (int q = 0; q < 4; ++q) s[q * 256 + t] += a[q];
        __syncthreads();
    }
    #pragma unroll
    for (int q = 0; q < 4; ++q) {
        int i = q * 256 + t;
        if (i < NBUK) base[i] = s[i] - v[q];
    }
}

__global__ __launch_bounds__(256) void k_scatter(const int* __restrict__ ei,
        const float* __restrict__ ew, const int* __restrict__ offD,
        const int* __restrict__ offS, const int* __restrict__ baseD,
        const int* __restrict__ baseS, long long* __restrict__ recD,
        long long* __restrict__ recS) {
    __shared__ int curD[NBUK], curS[NBUK];
    int t = threadIdx.x, blk = blockIdx.x;
    for (int b = t; b < NBUK; b += 256) {
        curD[b] = baseD[b] + offD[b * NBLK + blk];
        curS[b] = baseS[b] + offS[b * NBLK + blk];
    }
    __syncthreads();
    int e0 = blk * EPB;
    #pragma unroll
    for (int i = 0; i < 8; ++i) {
        int e = e0 + i * 256 + t;
        if (e < E_EDGES) {
            int sN = ei[e], dN = ei[E_EDGES + e];
            long long wb = (long long)(unsigned)__float_as_uint(ew[e]) << 32;
            int pD = atomicAdd(&curD[dN >> BSH], 1);
            recD[pD] = wb | (unsigned)((sN << BSH) | (dN & (BUKN - 1)));
            int pS = atomicAdd(&curS[sN >> BSH], 1);
            recS[pS] = wb | (unsigned)(sN & (BUKN - 1));
        }
    }
}

__global__ __launch_bounds__(256) void k_deg(const long long* __restrict__ recS,
        const int* __restrict__ totS, const int* __restrict__ baseS,
        float* __restrict__ dinv) {
    __shared__ float degL[BUKN];
    int t = threadIdx.x, b = blockIdx.x;
    if (t < BUKN) degL[t] = 0.f;
    __syncthreads();
    int st = baseS[b], n = totS[b];
    for (int i = t; i < n; i += 256) {
        long long r = recS[st + i];
        atomicAdd(&degL[(int)(r & (BUKN - 1))], __uint_as_float((unsigned)(r >> 32)));
    }
    __syncthreads();
    if (t < BUKN) {
        int node = b * BUKN + t;
        if (node < N_NODES) {
            float dg = degL[t];
            dinv[node] = dg > 0.f ? rsqrtf(dg) : 0.f;
        }
    }
}

// Bucket-grouped records -> exact CSR (cv sorted by dst node), val folded.
__global__ __launch_bounds__(256) void k_csr(const long long* __restrict__ recD,
        const int* __restrict__ totD, const int* __restrict__ baseD,
        const float* __restrict__ dinv, long long* __restrict__ cv,
        int* __restrict__ row_start) {
    __shared__ int cnt[BUKN], cur[BUKN];
    __shared__ float dL[BUKN];
    int t = threadIdx.x, b = blockIdx.x;
    if (t < BUKN) {
        cnt[t] = 0;
        int node = b * BUKN + t;
        dL[t] = (node < N_NODES) ? dinv[node] : 0.f;
    }
    __syncthreads();
    int st = baseD[b], n = totD[b];
    for (int i = t; i < n; i += 256)
        atomicAdd(&cnt[(int)(recD[st + i] & (BUKN - 1))], 1);
    __syncthreads();
    if (t < BUKN) {
        int x = cnt[t];
        int orig = x;
        #pragma unroll
        for (int off = 1; off < BUKN; off <<= 1) {
            int v = __shfl_up(x, off, 64);
            if ((t & 63) >= off) x += v;
        }
        cur[t] = x - orig;
        int node = b * BUKN + t;
        if (node < N_NODES) row_start[node] = st + (x - orig);
    }
    if (b == 0 && t == 0) row_start[N_NODES] = E_EDGES;
    __syncthreads();
    for (int i = t; i < n; i += 256) {
        long long r = recD[st + i];
        int m = (int)(r & 0xffffffffLL);
        float w = __uint_as_float((unsigned)(r >> 32));
        int rr = m & (BUKN - 1);
        int sN = m >> BSH;
        float val = -w * dinv[sN] * dL[rr];
        int pos = st + atomicAdd(&cur[rr], 1);
        cv[pos] = ((long long)__float_as_int(val) << 32) | (unsigned)sN;
    }
}

// SpMM: one wave per row; 16 lanes per edge, 4 edges per gather instruction.
// lane = 16*sub + q: sub = edge slot (0..3), q = channel quad (float4).
// Tail edges masked to (src=0,val=0): gathers hot X[0] line, adds 0.
template<int SCALE, int SUB>
__global__ __launch_bounds__(256) void k_spmm(
        const int* __restrict__ row_start, const long long* __restrict__ cv,
        const float* __restrict__ xin, const float* __restrict__ xprev,
        float* __restrict__ out) {
    int wid = (blockIdx.x << 2) + (threadIdx.x >> 6);
    int l = threadIdx.x & 63;
    if (wid >= N_NODES) return;
    int start = row_start[wid];
    int end   = row_start[wid + 1];
    int sub = l >> 4;        // edge slot in group
    int q   = l & 15;        // channel quad
    float4 acc = make_float4(0.f, 0.f, 0.f, 0.f);
    for (int j = start; j < end; j += 8) {
        int jA = j + sub;
        int jB = j + 4 + sub;
        long long pA = (jA < end) ? cv[jA] : 0LL;
        long long pB = (jB < end) ? cv[jB] : 0LL;
        float4 xA = *(const float4*)&xin[(size_t)(unsigned)(pA & 0xffffffffLL) * NC + q * 4];
        float4 xB = *(const float4*)&xin[(size_t)(unsigned)(pB & 0xffffffffLL) * NC + q * 4];
        float vA = __int_as_float((int)(pA >> 32));
        float vB = __int_as_float((int)(pB >> 32));
        acc.x = fmaf(vA, xA.x, acc.x);
        acc.y = fmaf(vA, xA.y, acc.y);
        acc.z = fmaf(vA, xA.z, acc.z);
        acc.w = fmaf(vA, xA.w, acc.w);
        acc.x = fmaf(vB, xB.x, acc.x);
        acc.y = fmaf(vB, xB.y, acc.y);
        acc.z = fmaf(vB, xB.z, acc.z);
        acc.w = fmaf(vB, xB.w, acc.w);
    }
    // fold the 4 edge slots: butterfly over lane bits 4,5
    #pragma unroll
    for (int m = 16; m <= 32; m <<= 1) {
        acc.x += __shfl_xor(acc.x, m, 64);
        acc.y += __shfl_xor(acc.y, m, 64);
        acc.z += __shfl_xor(acc.z, m, 64);
        acc.w += __shfl_xor(acc.w, m, 64);
    }
    if (sub == 0) {
        float4 r;
        r.x = (float)SCALE * acc.x;
        r.y = (float)SCALE * acc.y;
        r.z = (float)SCALE * acc.z;
        r.w = (float)SCALE * acc.w;
        if (SUB) {
            float4 xo = *(const float4*)&xprev[(size_t)wid * NC + q * 4];
            r.x -= xo.x; r.y -= xo.y; r.z -= xo.z; r.w -= xo.w;
        }
        *(float4*)&out[(size_t)wid * NC + q * 4] = r;
    }
}

// bf16x3 MFMA GRU: 64-node tile, 4 waves = 4 o-tiles of 16 channels.
__global__ __launch_bounds__(256) void k_gru(
        const float* __restrict__ X, const float* __restrict__ Tx1,
        const float* __restrict__ Tx2, const short* __restrict__ WB,
        const float* __restrict__ bxz, const float* __restrict__ bhz,
        const float* __restrict__ bxh, const float* __restrict__ bhh,
        float* __restrict__ out) {
    __shared__ short Ahi[64 * 64];
    __shared__ short Alo[64 * 64];
    int tid = threadIdx.x;
    int l = tid & 63;
    int w = tid >> 6;
    int node0 = blockIdx.x * 64;

    f32x4 accz[4], acch[4];
    #pragma unroll
    for (int mt = 0; mt < 4; ++mt) {
        accz[mt] = (f32x4){0.f, 0.f, 0.f, 0.f};
        acch[mt] = (f32x4){0.f, 0.f, 0.f, 0.f};
    }

    const float* ins[3] = {X, Tx1, Tx2};
    #pragma unroll 1
    for (int m = 0; m < 3; ++m) {
        __syncthreads();
        const float* ip = ins[m];
        #pragma unroll
        for (int r = 0; r < 4; ++r) {
            int fidx = r * 256 + tid;
            int n = fidx >> 4, c4 = fidx & 15;
            int gn = node0 + n;
            float4 v = make_float4(0.f, 0.f, 0.f, 0.f);
            if (gn < N_NODES) v = *(const float4*)&ip[(size_t)gn * 64 + c4 * 4];
            unsigned h0 = bf16rne(v.x), h1 = bf16rne(v.y),
                     h2 = bf16rne(v.z), h3 = bf16rne(v.w);
            unsigned q0 = bf16rne(v.x - __uint_as_float(h0 << 16));
            unsigned q1 = bf16rne(v.y - __uint_as_float(h1 << 16));
            unsigned q2 = bf16rne(v.z - __uint_as_float(h2 << 16));
            unsigned q3 = bf16rne(v.w - __uint_as_float(h3 << 16));
            int kk = (c4 * 4) ^ ((n & 7) << 3);
            *(uint2*)&Ahi[n * 64 + kk] = make_uint2(h0 | (h1 << 16), h2 | (h3 << 16));
            *(uint2*)&Alo[n * 64 + kk] = make_uint2(q0 | (q1 << 16), q2 | (q3 << 16));
        }
        __syncthreads();
        const short* wbm = WB + m * 4 * 4096;
        #pragma unroll
        for (int kt = 0; kt < 2; ++kt) {
            int k0 = kt * 32 + (l >> 4) * 8;
            bf16x8 ah[4], al[4];
            #pragma unroll
            for (int mt = 0; mt < 4; ++mt) {
                int row = mt * 16 + (l & 15);
                int kk = k0 ^ ((row & 7) << 3);
                ah[mt] = *(const bf16x8*)&Ahi[row * 64 + kk];
                al[mt] = *(const bf16x8*)&Alo[row * 64 + kk];
            }
            int o = w * 16 + (l & 15);
            {
                bf16x8 bh_ = *(const bf16x8*)&wbm[0 * 4096 + o * 64 + k0];
                bf16x8 bl_ = *(const bf16x8*)&wbm[1 * 4096 + o * 64 + k0];
                #pragma unroll
                for (int mt = 0; mt < 4; ++mt) {
                    accz[mt] = __builtin_amdgcn_mfma_f32_16x16x32_bf16(ah[mt], bh_, accz[mt], 0, 0, 0);
                    accz[mt] = __builtin_amdgcn_mfma_f32_16x16x32_bf16(ah[mt], bl_, accz[mt], 0, 0, 0);
                    accz[mt] = __builtin_amdgcn_mfma_f32_16x16x32_bf16(al[mt], bh_, accz[mt], 0, 0, 0);
                }
            }
            {
                bf16x8 bh_ = *(const bf16x8*)&wbm[2 * 4096 + o * 64 + k0];
                bf16x8 bl_ = *(const bf16x8*)&wbm[3 * 4096 + o * 64 + k0];
                #pragma unroll
                for (int mt = 0; mt < 4; ++mt) {
                    acch[mt] = __builtin_amdgcn_mfma_f32_16x16x32_bf16(ah[mt], bh_, acch[mt], 0, 0, 0);
                    acch[mt] = __builtin_amdgcn_mfma_f32_16x16x32_bf16(ah[mt], bl_, acch[mt], 0, 0, 0);
                    acch[mt] = __builtin_amdgcn_mfma_f32_16x16x32_bf16(al[mt], bh_, acch[mt], 0, 0, 0);
                }
            }
        }
    }

    int o = w * 16 + (l & 15);
    float bz = bxz[o] + bhz[o];
    float bh = bxh[o] + bhh[o];
    #pragma unroll
    for (int mt = 0; mt < 4; ++mt) {
        #pragma unroll
        for (int r = 0; r < 4; ++r) {
            int node = node0 + mt * 16 + (l >> 4) * 4 + r;
            if (node < N_NODES) {
                float z = accz[mt][r] + bz;
                float h = acch[mt][r] + bh;
                float sig = 1.f / (1.f + __expf(-z));
                float e2 = __expf(-2.f * h);
                float th = (1.f - e2) / (1.f + e2);
                out[(size_t)node * 64 + o] = (1.f - sig) * th;
            }
        }
    }
}

extern "C" void kernel_launch(void* const* d_in, const int* in_sizes, int n_in,
                              void* d_out, int out_size, void* d_ws, size_t ws_size,
                              hipStream_t stream) {
    const float* X   = (const float*)d_in[0];
    const int*   ei  = (const int*)d_in[1];
    const float* ew  = (const float*)d_in[2];
    const float* Wxz = (const float*)d_in[3];
    const float* Wxh = (const float*)d_in[7];
    const float* bxz = (const float*)d_in[9];
    const float* bhz = (const float*)d_in[10];
    const float* bxh = (const float*)d_in[13];
    const float* bhh = (const float*)d_in[14];
    float* out = (float*)d_out;

    float* ws_f = (float*)d_ws;
    int*   ws_i = (int*)d_ws;

    long long* cv       = (long long*)(ws_i + OFF_CV);
    int*       rowstart = ws_i + OFF_ROWSTART;
    int*       totD     = ws_i + OFF_TOTD;
    int*       baseD    = ws_i + OFF_BASED;
    int*       totS     = ws_i + OFF_TOTS;
    int*       baseS    = ws_i + OFF_BASES;
    float*     tx1      = ws_f + OFF_TX1;
    long long* recD     = (long long*)(ws_i + OFF_RECD);
    float*     dinv     = ws_f + OFF_DINV;
    int*       cntD     = ws_i + OFF_CNTD;
    float*     tx2      = ws_f + OFF_TX2;
    long long* recS     = (long long*)(ws_i + OFF_RECS);
    int*       cntS     = ws_i + OFF_CNTS;
    short*     WB       = (short*)(ws_i + OFF_WB);

    const int TB = 256;
    k_hist<<<NBLK + 6, TB, 0, stream>>>(ei, cntD, cntS, Wxz, Wxh, WB);
    k_scanPB<<<2 * NBUK, TB, 0, stream>>>(cntD, cntS, totD, totS);
    k_scanTot<<<2, TB, 0, stream>>>(totD, baseD, totS, baseS);
    k_scatter<<<NBLK, TB, 0, stream>>>(ei, ew, cntD, cntS, baseD, baseS, recD, recS);
    k_deg<<<NBUK, TB, 0, stream>>>(recS, totS, baseS, dinv);
    k_csr<<<NBUK, TB, 0, stream>>>(recD, totD, baseD, dinv, cv, rowstart);

    // Tx1 = L_hat @ X
    k_spmm<1, 0><<<(N_NODES + 3) / 4, TB, 0, stream>>>(rowstart, cv, X, X, tx1);
    // Tx2 = 2 * L_hat @ Tx1 - X
    k_spmm<2, 1><<<(N_NODES + 3) / 4, TB, 0, stream>>>(rowstart, cv, tx1, X, tx2);

    k_gru<<<NBUK, TB, 0, stream>>>(X, tx1, tx2, WB, bxz, bhz, bxh, bhh, out);
}